// Round 2
// baseline (1246.976 us; speedup 1.0000x reference)
//
#include <hip/hip_runtime.h>
#include <math.h>

namespace {

constexpr int Bn=2, CIc=16, COc=16, Hc=256, Wc=256, HIDc=64, C5c=320, HDc=64, WDc=64;
constexpr int SPc = HDc*WDc;            // 4096
constexpr int NPIXc = Bn*Hc*Wc;         // 131072
constexpr float EPSc = 1e-5f;

// ---- 4x4 mean downsample: x (B,CI,256,256) -> xd (B,CI,64,64) ----
__global__ void k_down(const float* __restrict__ x, float* __restrict__ xd){
  int idx = blockIdx.x*blockDim.x + threadIdx.x;
  if (idx >= Bn*CIc*SPc) return;
  int q = idx & 63, p = (idx>>6)&63, c = idx>>12;          // c = b*CI+i
  const float* xp = x + (c*Hc + p*4)*Wc + q*4;
  float s = 0.f;
  #pragma unroll
  for(int dy=0; dy<4; dy++)
    #pragma unroll
    for(int dx=0; dx<4; dx++) s += xp[dy*Wc+dx];
  xd[idx] = s * (1.f/16.f);
}

// ---- conv0 3x3 pad1 (CI->HID) + scalar PReLU ----
__global__ void k_conv0(const float* __restrict__ xd, const float* __restrict__ w,
                        const float* __restrict__ bias, const float* __restrict__ a0,
                        float* __restrict__ h){
  int idx = blockIdx.x*blockDim.x + threadIdx.x;
  if (idx >= Bn*HIDc*SPc) return;
  int q = idx&63, p=(idx>>6)&63, co=(idx>>12)&63, b=idx/(HIDc*SPc);
  float acc = bias[co];
  for(int ci=0; ci<CIc; ci++){
    const float* xp = xd + (b*CIc+ci)*SPc;
    const float* wp = w + (co*CIc+ci)*9;
    #pragma unroll
    for(int u=0; u<3; u++){
      int pp = p+u-1; if((unsigned)pp >= 64u) continue;
      #pragma unroll
      for(int v=0; v<3; v++){
        int qq = q+v-1; if((unsigned)qq >= 64u) continue;
        acc += xp[pp*64+qq] * wp[u*3+v];
      }
    }
  }
  float a = a0[0];
  h[idx] = acc >= 0.f ? acc : a*acc;
}

// ---- generic 1x1 conv ----
template<int CIN, int COUT>
__global__ void k_conv1x1(const float* __restrict__ in, const float* __restrict__ w,
                          const float* __restrict__ bias, float* __restrict__ out){
  int idx = blockIdx.x*blockDim.x + threadIdx.x;
  if (idx >= Bn*COUT*SPc) return;
  int s = idx & (SPc-1);
  int o = (idx>>12) % COUT;
  int b = idx / (COUT*SPc);
  const float* ip = in + b*CIN*SPc + s;
  const float* wp = w + o*CIN;
  float acc = bias[o];
  #pragma unroll 8
  for(int c=0; c<CIN; c++) acc += ip[c*SPc]*wp[c];
  out[idx] = acc;
}

// ---- depthwise 3x3 pad1 on C5 channels ----
__global__ void k_dw(const float* __restrict__ t, const float* __restrict__ w,
                     const float* __restrict__ bias, float* __restrict__ out){
  int idx = blockIdx.x*blockDim.x + threadIdx.x;
  if (idx >= Bn*C5c*SPc) return;
  int q = idx&63, p=(idx>>6)&63, c=(idx>>12)%C5c, b=idx/(C5c*SPc);
  const float* ip = t + (size_t)(b*C5c+c)*SPc;
  const float* wp = w + c*9;
  float acc = bias[c];
  #pragma unroll
  for(int u=0; u<3; u++){
    int pp = p+u-1; if((unsigned)pp >= 64u) continue;
    #pragma unroll
    for(int v=0; v<3; v++){
      int qq = q+v-1; if((unsigned)qq >= 64u) continue;
      acc += ip[pp*64+qq]*wp[u*3+v];
    }
  }
  out[idx] = acc;
}

// ---- per-channel mean/rstd over (B, perB) ----
__global__ void k_stats(const float* __restrict__ t, int C, int perB,
                        float* __restrict__ mean, float* __restrict__ rstd){
  int c = blockIdx.x;
  double s = 0.0, s2 = 0.0;
  for(int b=0; b<Bn; b++){
    const float* p = t + (size_t)(b*C + c)*perB;
    for(int i=threadIdx.x; i<perB; i+=blockDim.x){
      float v = p[i]; s += v; s2 += (double)v*(double)v;
    }
  }
  __shared__ double sh[256], sh2[256];
  sh[threadIdx.x]=s; sh2[threadIdx.x]=s2; __syncthreads();
  for(int off=128; off>0; off>>=1){
    if(threadIdx.x<off){ sh[threadIdx.x]+=sh[threadIdx.x+off]; sh2[threadIdx.x]+=sh2[threadIdx.x+off]; }
    __syncthreads();
  }
  if(threadIdx.x==0){
    double N = (double)(Bn*perB);
    double m = sh[0]/N;
    double v = sh2[0]/N - m*m;
    mean[c] = (float)m;
    rstd[c] = rsqrtf((float)v + EPSc);
  }
}

// ---- BN + PReLU in place ----
__global__ void k_bnprelu(float* __restrict__ t, int C,
                          const float* __restrict__ g, const float* __restrict__ bb,
                          const float* __restrict__ ap,
                          const float* __restrict__ mean, const float* __restrict__ rstd){
  int idx = blockIdx.x*blockDim.x + threadIdx.x;
  if (idx >= Bn*C*SPc) return;
  int c = (idx>>12) % C;
  float a = ap[0];
  float y = g[c]*(t[idx]-mean[c])*rstd[c] + bb[c];
  t[idx] = y >= 0.f ? y : a*y;
}

// ---- BN + PReLU + residual add into h ----
__global__ void k_bnprelu_add(const float* __restrict__ t, float* __restrict__ h,
                              const float* __restrict__ g, const float* __restrict__ bb,
                              const float* __restrict__ ap,
                              const float* __restrict__ mean, const float* __restrict__ rstd){
  int idx = blockIdx.x*blockDim.x + threadIdx.x;
  if (idx >= Bn*HIDc*SPc) return;
  int c = (idx>>12)&63;
  float a = ap[0];
  float y = g[c]*(t[idx]-mean[c])*rstd[c] + bb[c];
  y = y >= 0.f ? y : a*y;
  h[idx] += y;
}

// ---- head 1x1 conv (HID->512), writes gvol layout (b,z,y,ci,o,k) ----
__global__ void k_head(const float* __restrict__ h, const float* __restrict__ w,
                       const float* __restrict__ bias, float* __restrict__ gv){
  int idx = blockIdx.x*blockDim.x + threadIdx.x;
  if (idx >= Bn*512*SPc) return;
  int s = idx & (SPc-1), c = (idx>>12)&511, b = idx/(512*SPc);
  const float* ip = h + b*HIDc*SPc + s;
  const float* wp = w + c*HIDc;
  float acc = bias[c];
  #pragma unroll 8
  for(int k=0; k<HIDc; k++) acc += ip[k*SPc]*wp[k];
  int o = c>>5, ci = (c>>1)&15, kk = c&1;     // c = ((o*16+ci)*2+k)
  int p = s>>6, q = s&63;
  gv[((((size_t)(b*HDc+p)*WDc + q)*CIc + ci)*COc + o)*2 + kk] = acc;
}

// ---- trilinear slice + affine apply; writes pre-BN output to d_out ----
__global__ void k_slice(const float* __restrict__ x, const float* __restrict__ gv,
                        float* __restrict__ outp){
  int idx = blockIdx.x*blockDim.x + threadIdx.x;
  if (idx >= NPIXc) return;
  int wq = idx&255, hp = (idx>>8)&255, b = idx>>16;
  float py = hp*(63.f/255.f);
  int y0 = (int)py; float fy = py-(float)y0; int y1 = min(y0+1, 63);
  float px = wq*(15.f/255.f);
  int x0 = (int)px; float fx = px-(float)x0; int x1 = min(x0+1, 15);
  float acc[COc], bacc[COc];
  #pragma unroll
  for(int o=0;o<COc;o++){ acc[o]=0.f; bacc[o]=0.f; }
  const float* gb = gv + (size_t)b*(HDc*WDc*CIc*COc*2);
  for(int i=0; i<CIc; i++){
    float xv = x[((b*CIc+i)*Hc + hp)*Wc + wq];
    float g = fminf(fmaxf(xv, 0.f), 1.f);
    float pz = g*63.f;
    int z0 = (int)pz; float fz = pz-(float)z0; int z1 = min(z0+1, 63);
    #pragma unroll
    for(int zc=0; zc<2; zc++){
      int zz = zc ? z1 : z0; float wzv = zc ? fz : 1.f-fz;
      const float* gzp = gb + zz*(WDc*CIc*COc*2);
      #pragma unroll
      for(int yc=0; yc<2; yc++){
        int yy = yc ? y1 : y0; float wyv = (yc ? fy : 1.f-fy)*wzv;
        const float* gyp = gzp + yy*(CIc*COc*2);
        #pragma unroll
        for(int xc=0; xc<2; xc++){
          int xx = xc ? x1 : x0; float w8 = (xc ? fx : 1.f-fx)*wyv;
          float w8x = w8*xv;
          const float4* gp = (const float4*)(gyp + xx*(COc*2));
          #pragma unroll
          for(int j=0; j<8; j++){
            float4 v = gp[j];
            acc[2*j]   += w8x*v.x;  bacc[2*j]   += w8*v.y;
            acc[2*j+1] += w8x*v.z;  bacc[2*j+1] += w8*v.w;
          }
        }
      }
    }
  }
  #pragma unroll
  for(int o=0;o<COc;o++)
    outp[((b*COc+o)*Hc + hp)*Wc + wq] = acc[o] + bacc[o]*(1.f/16.f);
}

// ---- final BN + SiLU in place on d_out ----
__global__ void k_final(float* __restrict__ out, const float* __restrict__ g,
                        const float* __restrict__ bb, const float* __restrict__ mean,
                        const float* __restrict__ rstd){
  int idx = blockIdx.x*blockDim.x + threadIdx.x;
  if (idx >= Bn*COc*Hc*Wc) return;
  int c = (idx>>16)&15;
  float y = g[c]*(out[idx]-mean[c])*rstd[c] + bb[c];
  out[idx] = y / (1.f + expf(-y));
}

} // namespace

extern "C" void kernel_launch(void* const* d_in, const int* in_sizes, int n_in,
                              void* d_out, int out_size, void* d_ws, size_t ws_size,
                              hipStream_t stream){
  const float* x       = (const float*)d_in[0];
  const float* conv0_w = (const float*)d_in[1];
  const float* conv0_b = (const float*)d_in[2];
  const float* prelu0  = (const float*)d_in[3];
  const float* c1w  = (const float*)d_in[4];
  const float* c1b  = (const float*)d_in[5];
  const float* bn1g = (const float*)d_in[6];
  const float* bn1b = (const float*)d_in[7];
  const float* p1   = (const float*)d_in[8];
  const float* dww  = (const float*)d_in[9];
  const float* dwb  = (const float*)d_in[10];
  const float* bn2g = (const float*)d_in[11];
  const float* bn2b = (const float*)d_in[12];
  const float* p2   = (const float*)d_in[13];
  const float* c3w  = (const float*)d_in[14];
  const float* c3b  = (const float*)d_in[15];
  const float* bn3g = (const float*)d_in[16];
  const float* bn3b = (const float*)d_in[17];
  const float* p3   = (const float*)d_in[18];
  const float* hw   = (const float*)d_in[19];
  const float* hb   = (const float*)d_in[20];
  const float* obg  = (const float*)d_in[21];
  const float* obb  = (const float*)d_in[22];
  float* out = (float*)d_out;
  float* ws  = (float*)d_ws;

  // workspace layout (floats); gvol aliases t1 (dead by head time)
  float* xd   = ws;                       // 131072
  float* h    = xd + Bn*CIc*SPc;          // 524288
  float* mean = h  + Bn*HIDc*SPc;         // 512
  float* rstd = mean + 512;               // 512
  float* t1   = rstd + 512;               // 2621440
  float* t2   = t1 + Bn*C5c*SPc;          // 2621440
  float* ts   = t2 + Bn*C5c*SPc;          // 524288
  float* gv   = t1;                       // 4194304 (fits in t1+t2)

  auto cdiv = [](int a, int b){ return (a+b-1)/b; };
  const int T = 256;

  k_down <<<cdiv(Bn*CIc*SPc,T), T, 0, stream>>>(x, xd);
  k_conv0<<<cdiv(Bn*HIDc*SPc,T), T, 0, stream>>>(xd, conv0_w, conv0_b, prelu0, h);

  for(int i=0; i<3; i++){
    k_conv1x1<HIDc,C5c><<<cdiv(Bn*C5c*SPc,T), T, 0, stream>>>(h, c1w + i*C5c*HIDc, c1b + i*C5c, t1);
    k_stats  <<<C5c, T, 0, stream>>>(t1, C5c, SPc, mean, rstd);
    k_bnprelu<<<cdiv(Bn*C5c*SPc,T), T, 0, stream>>>(t1, C5c, bn1g+i*C5c, bn1b+i*C5c, p1+i, mean, rstd);

    k_dw     <<<cdiv(Bn*C5c*SPc,T), T, 0, stream>>>(t1, dww + i*C5c*9, dwb + i*C5c, t2);
    k_stats  <<<C5c, T, 0, stream>>>(t2, C5c, SPc, mean, rstd);
    k_bnprelu<<<cdiv(Bn*C5c*SPc,T), T, 0, stream>>>(t2, C5c, bn2g+i*C5c, bn2b+i*C5c, p2+i, mean, rstd);

    k_conv1x1<C5c,HIDc><<<cdiv(Bn*HIDc*SPc,T), T, 0, stream>>>(t2, c3w + i*HIDc*C5c, c3b + i*HIDc, ts);
    k_stats  <<<HIDc, T, 0, stream>>>(ts, HIDc, SPc, mean, rstd);
    k_bnprelu_add<<<cdiv(Bn*HIDc*SPc,T), T, 0, stream>>>(ts, h, bn3g+i*HIDc, bn3b+i*HIDc, p3+i, mean, rstd);
  }

  k_head <<<cdiv(Bn*512*SPc,T), T, 0, stream>>>(h, hw, hb, gv);
  k_slice<<<cdiv(NPIXc,T), T, 0, stream>>>(x, gv, out);
  k_stats<<<COc, T, 0, stream>>>(out, COc, Hc*Wc, mean, rstd);
  k_final<<<cdiv(Bn*COc*Hc*Wc,T), T, 0, stream>>>(out, obg, obb, mean, rstd);
}

// Round 8
// 985.047 us; speedup vs baseline: 1.2659x; 1.2659x over previous
//
#include <hip/hip_runtime.h>
#include <math.h>

namespace {

constexpr int Bn=2, CIc=16, COc=16, Hc=256, Wc=256, HIDc=64, C5c=320;
constexpr int SPc = 4096;               // 64*64
constexpr float EPSc = 1e-5f;

// ---- 4x4 mean downsample: x (B,16,256,256) -> xd (B,16,64,64) ----
__global__ void k_down(const float* __restrict__ x, float* __restrict__ xd){
  int idx = blockIdx.x*blockDim.x + threadIdx.x;
  if (idx >= Bn*CIc*SPc) return;
  int q = idx & 63, p = (idx>>6)&63, c = idx>>12;
  const float* xp = x + ((size_t)c*Hc + p*4)*Wc + q*4;
  float s = 0.f;
  #pragma unroll
  for(int dy=0; dy<4; dy++)
    #pragma unroll
    for(int dx=0; dx<4; dx++) s += xp[dy*Wc+dx];
  xd[idx] = s * (1.f/16.f);
}

// ---- conv0 3x3 pad1 (16->64) + scalar PReLU ----
__global__ void k_conv0(const float* __restrict__ xd, const float* __restrict__ w,
                        const float* __restrict__ bias, const float* __restrict__ a0,
                        float* __restrict__ h){
  int idx = blockIdx.x*blockDim.x + threadIdx.x;
  if (idx >= Bn*HIDc*SPc) return;
  int q = idx&63, p=(idx>>6)&63, co=(idx>>12)&63, b=idx/(HIDc*SPc);
  float acc = bias[co];
  for(int ci=0; ci<CIc; ci++){
    const float* xp = xd + (size_t)(b*CIc+ci)*SPc;
    const float* wp = w + (co*CIc+ci)*9;
    #pragma unroll
    for(int u=0; u<3; u++){
      int pp = p+u-1; if((unsigned)pp >= 64u) continue;
      #pragma unroll
      for(int v=0; v<3; v++){
        int qq = q+v-1; if((unsigned)qq >= 64u) continue;
        acc = fmaf(xp[pp*64+qq], wp[u*3+v], acc);
      }
    }
  }
  float a = a0[0];
  h[idx] = acc >= 0.f ? acc : a*acc;
}

// ---- fused 1x1 conv 64->320 + stat partials ----
// grid (8 og, 64 sj, Bn), 256 thr. Wave=osub handles 10 o over 64 s.
__global__ void k_c1(const float* __restrict__ h, const float* __restrict__ w,
                     const float* __restrict__ bias, float* __restrict__ t1,
                     float* __restrict__ pacc){
  __shared__ float lh[64*64];
  int og = blockIdx.x, sj = blockIdx.y, b = blockIdx.z;
  int tid = threadIdx.x;
  for(int it=0; it<4; ++it){
    int f4 = tid + it*256;               // c*16 + s4
    int c = f4>>4, s4 = f4&15;
    float4 v = *(const float4*)(h + (size_t)(b*64+c)*SPc + sj*64 + s4*4);
    *(float4*)(&lh[c*64 + s4*4]) = v;
  }
  __syncthreads();
  int osub = tid>>6, s = tid&63;
  int ob = og*40 + osub*10;
  float acc[10];
  #pragma unroll
  for(int j=0;j<10;j++) acc[j] = bias[ob+j];
  for(int c=0;c<64;c++){
    float hv = lh[c*64+s];
    #pragma unroll
    for(int j=0;j<10;j++) acc[j] = fmaf(hv, w[(ob+j)*64 + c], acc[j]);
  }
  #pragma unroll
  for(int j=0;j<10;j++){
    int o = ob+j;
    t1[(size_t)(b*320+o)*SPc + sj*64 + s] = acc[j];
    float sm = acc[j], sq = acc[j]*acc[j];
    #pragma unroll
    for(int d=1; d<64; d<<=1){ sm += __shfl_xor(sm,d); sq += __shfl_xor(sq,d); }
    if(s==0){
      pacc[o*128 + b*64 + sj]         = sm;   // P=128
      pacc[40960 + o*128 + b*64 + sj] = sq;   // CP = 320*128
    }
  }
}

// ---- finalize: partials -> fused BN scale/shift A,B (deterministic) ----
__global__ void k_fin(const float* __restrict__ pacc, int P, float invN,
                      const float* __restrict__ g, const float* __restrict__ bb,
                      float* __restrict__ A, float* __restrict__ B){
  __shared__ double sh[256], sh2[256];
  int c = blockIdx.x, C = gridDim.x, tid = threadIdx.x;
  double s=0.0, s2=0.0;
  for(int p=tid; p<P; p+=256){
    s  += (double)pacc[c*P+p];
    s2 += (double)pacc[C*P + c*P + p];
  }
  sh[tid]=s; sh2[tid]=s2; __syncthreads();
  for(int off=128; off>0; off>>=1){
    if(tid<off){ sh[tid]+=sh[tid+off]; sh2[tid]+=sh2[tid+off]; }
    __syncthreads();
  }
  if(tid==0){
    float m = (float)(sh[0]*(double)invN);
    float v = (float)(sh2[0]*(double)invN) - m*m;
    float r = rsqrtf(v + EPSc);
    float gc = g[c];
    A[c] = gc*r;
    B[c] = bb[c] - m*gc*r;
  }
}

// ---- depthwise 3x3 with BN1+PReLU1 on read + stat partials ----
// grid 10240 = (b*320+c)*16 + j
__global__ void k_dw_s(const float* __restrict__ t1, const float* __restrict__ w,
                       const float* __restrict__ bias, const float* __restrict__ A,
                       const float* __restrict__ Bb, const float* __restrict__ ap,
                       float* __restrict__ t2, float* __restrict__ pacc){
  int idx = blockIdx.x*256 + threadIdx.x;
  int q = idx&63, p=(idx>>6)&63, c=(idx>>12)%C5c, b=idx/(C5c*SPc);
  float a1 = A[c], b1 = Bb[c], al = ap[0];
  const float* ip = t1 + (size_t)(b*C5c+c)*SPc;
  const float* wp = w + c*9;
  float acc = bias[c];
  #pragma unroll
  for(int u=0; u<3; u++){
    int pp = p+u-1; if((unsigned)pp >= 64u) continue;
    #pragma unroll
    for(int v=0; v<3; v++){
      int qq = q+v-1; if((unsigned)qq >= 64u) continue;
      float y = fmaf(ip[pp*64+qq], a1, b1);
      y = y >= 0.f ? y : al*y;
      acc = fmaf(y, wp[u*3+v], acc);
    }
  }
  t2[idx] = acc;
  // deterministic block stats (single channel per block)
  float sm = acc, sq = acc*acc;
  #pragma unroll
  for(int d=1; d<64; d<<=1){ sm += __shfl_xor(sm,d); sq += __shfl_xor(sq,d); }
  __shared__ float sred[8];
  int wv = threadIdx.x>>6, ln = threadIdx.x&63;
  if(ln==0){ sred[wv]=sm; sred[4+wv]=sq; }
  __syncthreads();
  if(threadIdx.x==0){
    float S = ((sred[0]+sred[1])+(sred[2]+sred[3]));
    float Q = ((sred[4]+sred[5])+(sred[6]+sred[7]));
    int j = blockIdx.x & 15;
    pacc[c*32 + b*16 + j]         = S;   // P=32
    pacc[10240 + c*32 + b*16 + j] = Q;   // CP = 320*32
  }
}

// ---- fused 1x1 conv 320->64 with BN2+PReLU2 on read + stat partials ----
// grid (64 sj, Bn), 256 thr; wave og handles 16 o over 64 s; 5 c-rounds.
__global__ void k_c3(const float* __restrict__ t2, const float* __restrict__ w,
                     const float* __restrict__ bias, const float* __restrict__ A,
                     const float* __restrict__ Bb, const float* __restrict__ ap,
                     float* __restrict__ ts, float* __restrict__ pacc){
  __shared__ float lc[64*64];
  int sj = blockIdx.x, b = blockIdx.y, tid = threadIdx.x;
  float al = ap[0];
  int og = tid>>6, s = tid&63;
  float acc[16];
  #pragma unroll
  for(int j=0;j<16;j++) acc[j] = bias[og*16+j];
  for(int cc=0; cc<5; cc++){
    __syncthreads();
    for(int it=0; it<16; ++it){
      int f = tid + it*256;              // c*64 + ss
      int c = f>>6, ss = f&63;
      int cg = cc*64 + c;
      float v = t2[(size_t)(b*C5c+cg)*SPc + sj*64 + ss];
      float y = fmaf(v, A[cg], Bb[cg]);
      lc[c*64+ss] = y >= 0.f ? y : al*y;
    }
    __syncthreads();
    for(int c=0;c<64;c++){
      float hv = lc[c*64+s];
      #pragma unroll
      for(int j=0;j<16;j++)
        acc[j] = fmaf(hv, w[(og*16+j)*C5c + cc*64 + c], acc[j]);
    }
  }
  #pragma unroll
  for(int j=0;j<16;j++){
    int o = og*16+j;
    ts[(size_t)(b*64+o)*SPc + sj*64 + s] = acc[j];
    float sm = acc[j], sq = acc[j]*acc[j];
    #pragma unroll
    for(int d=1; d<64; d<<=1){ sm += __shfl_xor(sm,d); sq += __shfl_xor(sq,d); }
    if(s==0){
      pacc[o*128 + b*64 + sj]        = sm;  // P=128
      pacc[8192 + o*128 + b*64 + sj] = sq;  // CP = 64*128
    }
  }
}

// ---- BN3 + PReLU3 + residual add into h ----
__global__ void k_addres(const float* __restrict__ ts, float* __restrict__ h,
                         const float* __restrict__ A, const float* __restrict__ Bb,
                         const float* __restrict__ ap){
  int idx = blockIdx.x*256 + threadIdx.x;
  int c = (idx>>12)&63;
  float y = fmaf(ts[idx], A[c], Bb[c]);
  float al = ap[0];
  y = y >= 0.f ? y : al*y;
  h[idx] += y;
}

// ---- head 1x1 conv (64->512) writing z-innermost gvol ----
// gv: [b][y=q(64)][x=ci(16)][ok(32)][z=p(64)]
__global__ void k_head_t(const float* __restrict__ h, const float* __restrict__ w,
                         const float* __restrict__ bias, float* __restrict__ gv){
  __shared__ float sb0[64*65], sb1[64*65];
  int bid = blockIdx.x;            // (b*16 + o)*16 + ci
  int ci = bid & 15, o = (bid>>4) & 15, b = bid >> 8;
  int c0 = (o*16 + ci)*2, c1 = c0 + 1;
  const float* hp0 = h + (size_t)b*HIDc*SPc;
  const float* w0 = w + (size_t)c0*HIDc;
  const float* w1 = w + (size_t)c1*HIDc;
  float b0 = bias[c0], b1 = bias[c1];
  int tid = threadIdx.x;
  for(int j=0; j<16; j++){
    int s = tid + j*256;           // s = p*64 + q
    float a0 = b0, a1 = b1;
    #pragma unroll 8
    for(int kc=0; kc<HIDc; kc++){
      float hv = hp0[kc*SPc + s];
      a0 = fmaf(hv, w0[kc], a0);
      a1 = fmaf(hv, w1[kc], a1);
    }
    int pad = s + (s>>6);
    sb0[pad] = a0; sb1[pad] = a1;
  }
  __syncthreads();
  float* gb = gv + (size_t)b*(64*16*32*64);
  for(int j=0; j<16; j++){
    int t = tid + j*256;
    int q = t>>6, p = t&63;
    size_t base = (((size_t)q*16 + ci)*32 + o*2)*64 + p;
    gb[base]      = sb0[p*65 + q];
    gb[base + 64] = sb1[p*65 + q];
  }
}

// ---- tiled slice: 8 rows x 17 cols (x0 = wq/17 exact) + stat partials ----
// grid (16 sseg, 32 rblk, Bn), 256 thr, 64KB LDS = 4y x 2x chunks of [32ok][64z]
__global__ void k_slice(const float* __restrict__ x, const float* __restrict__ gv,
                        float* __restrict__ outp, float* __restrict__ pacc){
  __shared__ float lds[8*2048];
  int sseg = blockIdx.x;
  int r0 = blockIdx.y*8;
  int b = blockIdx.z;
  int tid = threadIdx.x;
  const float* gb = gv + (size_t)b*(64*16*32*64);
  int ybase = (r0*63)/255;
  for(int it=0; it<16; ++it){
    int t = tid + it*256;
    int cix = t>>9, off = t&511;
    int yi = cix>>1, xi = cix&1;
    int ys = min(ybase+yi, 63);
    int xs = min(sseg+xi, 15);
    const float4* src = (const float4*)(gb + (((size_t)(ys*16+xs))<<11));
    *(float4*)(&lds[(cix<<11) + off*4]) = src[off];
  }
  __syncthreads();

  bool act = tid < 136;
  int lr = act ? tid/17 : 0;
  int lc = act ? tid - lr*17 : 0;
  int wq = sseg*17 + lc;
  if(wq > 255){ act = false; lc = 0; wq = sseg*17; }
  int hp = r0 + lr;

  float py = hp*(63.f/255.f);
  int y0 = (int)py; float fy = py - (float)y0;
  int y1 = min(y0+1, 63);
  int yA = y0 - ybase, yB = y1 - ybase;
  float fx = lc*(1.f/17.f);
  int xB = min(sseg+1,15) - sseg;
  int   cb[4]; float cw[4];
  cb[0] = (yA*2)<<11;    cw[0] = (1.f-fy)*(1.f-fx);
  cb[1] = (yA*2+xB)<<11; cw[1] = (1.f-fy)*fx;
  cb[2] = (yB*2)<<11;    cw[2] = fy*(1.f-fx);
  cb[3] = (yB*2+xB)<<11; cw[3] = fy*fx;

  float acc[COc], bacc[COc];
  #pragma unroll
  for(int o=0;o<COc;o++){ acc[o]=0.f; bacc[o]=0.f; }

  for(int i=0; i<CIc; i++){
    float xv = x[((size_t)(b*CIc+i)*Hc + hp)*Wc + wq];
    float g = fminf(fmaxf(xv, 0.f), 1.f);
    float pz = g*63.f;
    int z0 = (int)pz; float fz = pz - (float)z0;
    int dz = (z0 < 63) ? 1 : 0;
    #pragma unroll
    for(int c4=0; c4<4; c4++){
      int base = cb[c4] + z0;
      float w8 = cw[c4];
      float wz0 = w8*(1.f-fz), wz1 = w8*fz;
      float wz0x = wz0*xv,     wz1x = wz1*xv;
      #pragma unroll
      for(int o=0; o<COc; o++){
        int a0 = base + o*128;
        acc[o]  = fmaf(wz0x, lds[a0],    fmaf(wz1x, lds[a0+dz],    acc[o]));
        bacc[o] = fmaf(wz0,  lds[a0+64], fmaf(wz1,  lds[a0+64+dz], bacc[o]));
      }
    }
  }
  float vout[COc];
  #pragma unroll
  for(int o=0;o<COc;o++) vout[o] = acc[o] + bacc[o]*(1.f/16.f);
  if(act){
    #pragma unroll
    for(int o=0;o<COc;o++)
      outp[((size_t)(b*COc+o)*Hc + hp)*Wc + wq] = vout[o];
  }
  // deterministic stats (reuse lds as scratch)
  __syncthreads();
  int wv = tid>>6, ln = tid&63;
  for(int o=0;o<COc;o++){
    float v = act ? vout[o] : 0.f;
    float sm = v, sq = v*v;
    #pragma unroll
    for(int d=1; d<64; d<<=1){ sm += __shfl_xor(sm,d); sq += __shfl_xor(sq,d); }
    if(ln==0){ lds[(wv*16+o)*2] = sm; lds[(wv*16+o)*2+1] = sq; }
  }
  __syncthreads();
  if(tid < 32){
    int o = tid>>1, kd = tid&1;
    float S = ((lds[(0*16+o)*2+kd] + lds[(1*16+o)*2+kd])
             + (lds[(2*16+o)*2+kd] + lds[(3*16+o)*2+kd]));
    int blk = (b*32 + blockIdx.y)*16 + sseg;         // P=1024
    pacc[kd*16384 + o*1024 + blk] = S;               // CP = 16*1024
  }
}

// ---- final BN + SiLU in place on d_out ----
__global__ void k_final(float* __restrict__ out, const float* __restrict__ A,
                        const float* __restrict__ B){
  int idx = blockIdx.x*256 + threadIdx.x;
  int c = (idx>>16)&15;
  float y = fmaf(out[idx], A[c], B[c]);
  out[idx] = y / (1.f + expf(-y));
}

} // namespace

extern "C" void kernel_launch(void* const* d_in, const int* in_sizes, int n_in,
                              void* d_out, int out_size, void* d_ws, size_t ws_size,
                              hipStream_t stream){
  const float* x       = (const float*)d_in[0];
  const float* conv0_w = (const float*)d_in[1];
  const float* conv0_b = (const float*)d_in[2];
  const float* prelu0  = (const float*)d_in[3];
  const float* c1w  = (const float*)d_in[4];
  const float* c1b  = (const float*)d_in[5];
  const float* bn1g = (const float*)d_in[6];
  const float* bn1b = (const float*)d_in[7];
  const float* p1   = (const float*)d_in[8];
  const float* dww  = (const float*)d_in[9];
  const float* dwb  = (const float*)d_in[10];
  const float* bn2g = (const float*)d_in[11];
  const float* bn2b = (const float*)d_in[12];
  const float* p2   = (const float*)d_in[13];
  const float* c3w  = (const float*)d_in[14];
  const float* c3b  = (const float*)d_in[15];
  const float* bn3g = (const float*)d_in[16];
  const float* bn3b = (const float*)d_in[17];
  const float* p3   = (const float*)d_in[18];
  const float* hw   = (const float*)d_in[19];
  const float* hb   = (const float*)d_in[20];
  const float* obg  = (const float*)d_in[21];
  const float* obb  = (const float*)d_in[22];
  float* out = (float*)d_out;
  float* ws  = (float*)d_ws;

  // workspace (floats)
  float* xd   = ws;                 // 131072
  float* h    = xd + 131072;        // 524288
  float* A    = h  + 524288;        // 320
  float* B    = A  + 320;           // 320
  float* pacc = B  + 320;           // 81920
  float* t1   = pacc + 81920;       // 2621440
  float* t2   = t1 + 2621440;       // 2621440
  float* ts   = t2 + 2621440;       // 524288
  float* gv   = t1;                 // 4194304 aliases t1+t2 (dead by head)

  k_down <<<512,  256, 0, stream>>>(x, xd);
  k_conv0<<<2048, 256, 0, stream>>>(xd, conv0_w, conv0_b, prelu0, h);

  for(int i=0; i<3; i++){
    k_c1  <<<dim3(8,64,Bn), 256, 0, stream>>>(h, c1w + i*20480, c1b + i*320, t1, pacc);
    k_fin <<<320, 256, 0, stream>>>(pacc, 128, 1.f/8192.f, bn1g+i*320, bn1b+i*320, A, B);
    k_dw_s<<<10240, 256, 0, stream>>>(t1, dww + i*2880, dwb + i*320, A, B, p1+i, t2, pacc);
    k_fin <<<320, 256, 0, stream>>>(pacc, 32, 1.f/8192.f, bn2g+i*320, bn2b+i*320, A, B);
    k_c3  <<<dim3(64,Bn), 256, 0, stream>>>(t2, c3w + i*20480, c3b + i*64, A, B, p2+i, ts, pacc);
    k_fin <<<64, 256, 0, stream>>>(pacc, 128, 1.f/8192.f, bn3g+i*64, bn3b+i*64, A, B);
    k_addres<<<2048, 256, 0, stream>>>(ts, h, A, B, p3+i);
  }

  k_head_t<<<512, 256, 0, stream>>>(h, hw, hb, gv);
  k_slice <<<dim3(16,32,Bn), 256, 0, stream>>>(x, gv, out, pacc);
  k_fin   <<<16, 256, 0, stream>>>(pacc, 1024, 1.f/131072.f, obg, obb, A, B);
  k_final <<<8192, 256, 0, stream>>>(out, A, B);
}

// Round 9
// 665.564 us; speedup vs baseline: 1.8736x; 1.4800x over previous
//
#include <hip/hip_runtime.h>
#include <math.h>

namespace {

constexpr int Bn=2, CIc=16, COc=16, Hc=256, Wc=256, HIDc=64, C5c=320;
constexpr int SPc = 4096;               // 64*64
constexpr float EPSc = 1e-5f;

// ---- 4x4 mean downsample: x (B,16,256,256) -> xd (B,16,64,64) ----
__global__ void k_down(const float* __restrict__ x, float* __restrict__ xd){
  int idx = blockIdx.x*blockDim.x + threadIdx.x;
  if (idx >= Bn*CIc*SPc) return;
  int q = idx & 63, p = (idx>>6)&63, c = idx>>12;
  const float* xp = x + ((size_t)c*Hc + p*4)*Wc + q*4;
  float s = 0.f;
  #pragma unroll
  for(int dy=0; dy<4; dy++)
    #pragma unroll
    for(int dx=0; dx<4; dx++) s += xp[dy*Wc+dx];
  xd[idx] = s * (1.f/16.f);
}

// ---- conv0 3x3 pad1 (16->64) + scalar PReLU ----
__global__ void k_conv0(const float* __restrict__ xd, const float* __restrict__ w,
                        const float* __restrict__ bias, const float* __restrict__ a0,
                        float* __restrict__ h){
  int idx = blockIdx.x*blockDim.x + threadIdx.x;
  if (idx >= Bn*HIDc*SPc) return;
  int q = idx&63, p=(idx>>6)&63, co=(idx>>12)&63, b=idx/(HIDc*SPc);
  float acc = bias[co];
  for(int ci=0; ci<CIc; ci++){
    const float* xp = xd + (size_t)(b*CIc+ci)*SPc;
    const float* wp = w + (co*CIc+ci)*9;
    #pragma unroll
    for(int u=0; u<3; u++){
      int pp = p+u-1; if((unsigned)pp >= 64u) continue;
      #pragma unroll
      for(int v=0; v<3; v++){
        int qq = q+v-1; if((unsigned)qq >= 64u) continue;
        acc = fmaf(xp[pp*64+qq], wp[u*3+v], acc);
      }
    }
  }
  float a = a0[0];
  h[idx] = acc >= 0.f ? acc : a*acc;
}

// ---- fused 1x1 conv 64->320 + stat partials ----
// grid (8 og, 64 sj, Bn), 256 thr. Wave=osub handles 10 o over 64 s.
__global__ void k_c1(const float* __restrict__ h, const float* __restrict__ w,
                     const float* __restrict__ bias, float* __restrict__ t1,
                     float* __restrict__ pacc){
  __shared__ float lh[64*64];
  int og = blockIdx.x, sj = blockIdx.y, b = blockIdx.z;
  int tid = threadIdx.x;
  for(int it=0; it<4; ++it){
    int f4 = tid + it*256;               // c*16 + s4
    int c = f4>>4, s4 = f4&15;
    float4 v = *(const float4*)(h + (size_t)(b*64+c)*SPc + sj*64 + s4*4);
    *(float4*)(&lh[c*64 + s4*4]) = v;
  }
  __syncthreads();
  int osub = tid>>6, s = tid&63;
  int ob = og*40 + osub*10;
  float acc[10];
  #pragma unroll
  for(int j=0;j<10;j++) acc[j] = bias[ob+j];
  for(int c=0;c<64;c++){
    float hv = lh[c*64+s];
    #pragma unroll
    for(int j=0;j<10;j++) acc[j] = fmaf(hv, w[(ob+j)*64 + c], acc[j]);
  }
  #pragma unroll
  for(int j=0;j<10;j++){
    int o = ob+j;
    t1[(size_t)(b*320+o)*SPc + sj*64 + s] = acc[j];
    float sm = acc[j], sq = acc[j]*acc[j];
    #pragma unroll
    for(int d=1; d<64; d<<=1){ sm += __shfl_xor(sm,d); sq += __shfl_xor(sq,d); }
    if(s==0){
      pacc[o*128 + b*64 + sj]         = sm;   // P=128
      pacc[40960 + o*128 + b*64 + sj] = sq;   // CP = 320*128
    }
  }
}

// ---- finalize: partials -> fused BN scale/shift A,B (deterministic) ----
__global__ void k_fin(const float* __restrict__ pacc, int P, float invN,
                      const float* __restrict__ g, const float* __restrict__ bb,
                      float* __restrict__ A, float* __restrict__ B){
  __shared__ double sh[256], sh2[256];
  int c = blockIdx.x, C = gridDim.x, tid = threadIdx.x;
  double s=0.0, s2=0.0;
  for(int p=tid; p<P; p+=256){
    s  += (double)pacc[c*P+p];
    s2 += (double)pacc[C*P + c*P + p];
  }
  sh[tid]=s; sh2[tid]=s2; __syncthreads();
  for(int off=128; off>0; off>>=1){
    if(tid<off){ sh[tid]+=sh[tid+off]; sh2[tid]+=sh2[tid+off]; }
    __syncthreads();
  }
  if(tid==0){
    float m = (float)(sh[0]*(double)invN);
    float v = (float)(sh2[0]*(double)invN) - m*m;
    float r = rsqrtf(v + EPSc);
    float gc = g[c];
    A[c] = gc*r;
    B[c] = bb[c] - m*gc*r;
  }
}

// ---- depthwise 3x3 with BN1+PReLU1 on read + stat partials ----
// grid 10240 = (b*320+c)*16 + j
__global__ void k_dw_s(const float* __restrict__ t1, const float* __restrict__ w,
                       const float* __restrict__ bias, const float* __restrict__ A,
                       const float* __restrict__ Bb, const float* __restrict__ ap,
                       float* __restrict__ t2, float* __restrict__ pacc){
  int idx = blockIdx.x*256 + threadIdx.x;
  int q = idx&63, p=(idx>>6)&63, c=(idx>>12)%C5c, b=idx/(C5c*SPc);
  float a1 = A[c], b1 = Bb[c], al = ap[0];
  const float* ip = t1 + (size_t)(b*C5c+c)*SPc;
  const float* wp = w + c*9;
  float acc = bias[c];
  #pragma unroll
  for(int u=0; u<3; u++){
    int pp = p+u-1; if((unsigned)pp >= 64u) continue;
    #pragma unroll
    for(int v=0; v<3; v++){
      int qq = q+v-1; if((unsigned)qq >= 64u) continue;
      float y = fmaf(ip[pp*64+qq], a1, b1);
      y = y >= 0.f ? y : al*y;
      acc = fmaf(y, wp[u*3+v], acc);
    }
  }
  t2[idx] = acc;
  // deterministic block stats (single channel per block)
  float sm = acc, sq = acc*acc;
  #pragma unroll
  for(int d=1; d<64; d<<=1){ sm += __shfl_xor(sm,d); sq += __shfl_xor(sq,d); }
  __shared__ float sred[8];
  int wv = threadIdx.x>>6, ln = threadIdx.x&63;
  if(ln==0){ sred[wv]=sm; sred[4+wv]=sq; }
  __syncthreads();
  if(threadIdx.x==0){
    float S = ((sred[0]+sred[1])+(sred[2]+sred[3]));
    float Q = ((sred[4]+sred[5])+(sred[6]+sred[7]));
    int j = blockIdx.x & 15;
    pacc[c*32 + b*16 + j]         = S;   // P=32
    pacc[10240 + c*32 + b*16 + j] = Q;   // CP = 320*32
  }
}

// ---- fused 1x1 conv 320->64 with BN2+PReLU2 on read + stat partials ----
// grid (256 sjf, Bn), 256 thr. Block: 16 px, all 320 in-ch (4 rounds of 80),
// LDS = in-tile 320x16 staged per round (80x16) + weight subtile 64x80.
__global__ void k_c3(const float* __restrict__ t2, const float* __restrict__ w,
                     const float* __restrict__ bias, const float* __restrict__ A,
                     const float* __restrict__ Bb, const float* __restrict__ ap,
                     float* __restrict__ ts, float* __restrict__ pacc){
  __shared__ float li[80*16];     // 5 KB  [c80][s]
  __shared__ float lw[64*80];     // 20 KB [o][c80]
  int sjf = blockIdx.x, b = blockIdx.y, tid = threadIdx.x;
  float al = ap[0];
  int og = tid>>4, s = tid&15;    // og 0..15, s 0..15
  float acc[4];
  #pragma unroll
  for(int j=0;j<4;j++) acc[j] = bias[og*4+j];

  for(int cc=0; cc<4; cc++){
    __syncthreads();
    // stage input 80 ch x 16 px (BN2+PReLU2 applied)
    {
      int t = tid;                 // 320 float4 jobs, 256 threads -> +64 second pass
      for(int r=0; r<2; ++r, t+=256){
        if(t < 320){
          int c = t>>2, k = t&3;
          int cg = cc*80 + c;
          float4 v = *(const float4*)(t2 + (size_t)(b*C5c+cg)*SPc + sjf*16 + k*4);
          float4 y;
          float a1 = A[cg], b1 = Bb[cg];
          y.x = fmaf(v.x, a1, b1); y.x = y.x>=0.f ? y.x : al*y.x;
          y.y = fmaf(v.y, a1, b1); y.y = y.y>=0.f ? y.y : al*y.y;
          y.z = fmaf(v.z, a1, b1); y.z = y.z>=0.f ? y.z : al*y.z;
          y.w = fmaf(v.w, a1, b1); y.w = y.w>=0.f ? y.w : al*y.w;
          *(float4*)(&li[c*16 + k*4]) = y;
        }
      }
    }
    // stage weights 64 o x 80 c  (w[o*320 + cc*80 + c], rows contiguous)
    for(int t = tid; t < 1280; t += 256){
      int o = t/20, k = t%20;      // 20 float4 per o-row
      float4 v = *(const float4*)(w + (size_t)o*C5c + cc*80 + k*4);
      *(float4*)(&lw[o*80 + k*4]) = v;
    }
    __syncthreads();
    for(int c=0; c<80; c++){
      float hv = li[c*16 + s];
      #pragma unroll
      for(int j=0;j<4;j++)
        acc[j] = fmaf(hv, lw[(og*4+j)*80 + c], acc[j]);
    }
  }

  // write + deterministic per-block stats (16-lane groups share og)
  #pragma unroll
  for(int j=0;j<4;j++){
    int o = og*4+j;
    ts[(size_t)(b*64+o)*SPc + sjf*16 + s] = acc[j];
    float sm = acc[j], sq = acc[j]*acc[j];
    #pragma unroll
    for(int d=1; d<16; d<<=1){ sm += __shfl_xor(sm,d); sq += __shfl_xor(sq,d); }
    if(s==0){
      pacc[o*512 + b*256 + sjf]         = sm;  // P=512
      pacc[32768 + o*512 + b*256 + sjf] = sq;  // CP = 64*512
    }
  }
}

// ---- BN3 + PReLU3 + residual add into h ----
__global__ void k_addres(const float* __restrict__ ts, float* __restrict__ h,
                         const float* __restrict__ A, const float* __restrict__ Bb,
                         const float* __restrict__ ap){
  int idx = blockIdx.x*256 + threadIdx.x;
  int c = (idx>>12)&63;
  float y = fmaf(ts[idx], A[c], Bb[c]);
  float al = ap[0];
  y = y >= 0.f ? y : al*y;
  h[idx] += y;
}

// ---- head 1x1 conv (64->512) writing z-innermost gvol ----
// gv: [b][y=q(64)][x=ci(16)][ok(32)][z=p(64)]
__global__ void k_head_t(const float* __restrict__ h, const float* __restrict__ w,
                         const float* __restrict__ bias, float* __restrict__ gv){
  __shared__ float sb0[64*65], sb1[64*65];
  int bid = blockIdx.x;            // (b*16 + o)*16 + ci
  int ci = bid & 15, o = (bid>>4) & 15, b = bid >> 8;
  int c0 = (o*16 + ci)*2, c1 = c0 + 1;
  const float* hp0 = h + (size_t)b*HIDc*SPc;
  const float* w0 = w + (size_t)c0*HIDc;
  const float* w1 = w + (size_t)c1*HIDc;
  float b0 = bias[c0], b1 = bias[c1];
  int tid = threadIdx.x;
  for(int j=0; j<16; j++){
    int s = tid + j*256;           // s = p*64 + q
    float a0 = b0, a1 = b1;
    #pragma unroll 8
    for(int kc=0; kc<HIDc; kc++){
      float hv = hp0[kc*SPc + s];
      a0 = fmaf(hv, w0[kc], a0);
      a1 = fmaf(hv, w1[kc], a1);
    }
    int pad = s + (s>>6);
    sb0[pad] = a0; sb1[pad] = a1;
  }
  __syncthreads();
  float* gb = gv + (size_t)b*(64*16*32*64);
  for(int j=0; j<16; j++){
    int t = tid + j*256;
    int q = t>>6, p = t&63;
    size_t base = (((size_t)q*16 + ci)*32 + o*2)*64 + p;
    gb[base]      = sb0[p*65 + q];
    gb[base + 64] = sb1[p*65 + q];
  }
}

// ---- tiled slice: 8 rows x 17 cols (x0 = wq/17 exact) + stat partials ----
// grid (16 sseg, 32 rblk, Bn), 256 thr, 64KB LDS = 4y x 2x chunks of [32ok][64z]
__global__ void k_slice(const float* __restrict__ x, const float* __restrict__ gv,
                        float* __restrict__ outp, float* __restrict__ pacc){
  __shared__ float lds[8*2048];
  int sseg = blockIdx.x;
  int r0 = blockIdx.y*8;
  int b = blockIdx.z;
  int tid = threadIdx.x;
  const float* gb = gv + (size_t)b*(64*16*32*64);
  int ybase = (r0*63)/255;
  for(int it=0; it<16; ++it){
    int t = tid + it*256;
    int cix = t>>9, off = t&511;
    int yi = cix>>1, xi = cix&1;
    int ys = min(ybase+yi, 63);
    int xs = min(sseg+xi, 15);
    const float4* src = (const float4*)(gb + (((size_t)(ys*16+xs))<<11));
    *(float4*)(&lds[(cix<<11) + off*4]) = src[off];
  }
  __syncthreads();

  bool act = tid < 136;
  int lr = act ? tid/17 : 0;
  int lc = act ? tid - lr*17 : 0;
  int wq = sseg*17 + lc;
  if(wq > 255){ act = false; lc = 0; wq = sseg*17; }
  int hp = r0 + lr;

  float py = hp*(63.f/255.f);
  int y0 = (int)py; float fy = py - (float)y0;
  int y1 = min(y0+1, 63);
  int yA = y0 - ybase, yB = y1 - ybase;
  float fx = lc*(1.f/17.f);
  int xB = min(sseg+1,15) - sseg;
  int   cb[4]; float cw[4];
  cb[0] = (yA*2)<<11;    cw[0] = (1.f-fy)*(1.f-fx);
  cb[1] = (yA*2+xB)<<11; cw[1] = (1.f-fy)*fx;
  cb[2] = (yB*2)<<11;    cw[2] = fy*(1.f-fx);
  cb[3] = (yB*2+xB)<<11; cw[3] = fy*fx;

  float acc[COc], bacc[COc];
  #pragma unroll
  for(int o=0;o<COc;o++){ acc[o]=0.f; bacc[o]=0.f; }

  for(int i=0; i<CIc; i++){
    float xv = x[((size_t)(b*CIc+i)*Hc + hp)*Wc + wq];
    float g = fminf(fmaxf(xv, 0.f), 1.f);
    float pz = g*63.f;
    int z0 = (int)pz; float fz = pz - (float)z0;
    int dz = (z0 < 63) ? 1 : 0;
    #pragma unroll
    for(int c4=0; c4<4; c4++){
      int base = cb[c4] + z0;
      float w8 = cw[c4];
      float wz0 = w8*(1.f-fz), wz1 = w8*fz;
      float wz0x = wz0*xv,     wz1x = wz1*xv;
      #pragma unroll
      for(int o=0; o<COc; o++){
        int a0 = base + o*128;
        acc[o]  = fmaf(wz0x, lds[a0],    fmaf(wz1x, lds[a0+dz],    acc[o]));
        bacc[o] = fmaf(wz0,  lds[a0+64], fmaf(wz1,  lds[a0+64+dz], bacc[o]));
      }
    }
  }
  float vout[COc];
  #pragma unroll
  for(int o=0;o<COc;o++) vout[o] = acc[o] + bacc[o]*(1.f/16.f);
  if(act){
    #pragma unroll
    for(int o=0;o<COc;o++)
      outp[((size_t)(b*COc+o)*Hc + hp)*Wc + wq] = vout[o];
  }
  // deterministic stats (reuse lds as scratch)
  __syncthreads();
  int wv = tid>>6, ln = tid&63;
  for(int o=0;o<COc;o++){
    float v = act ? vout[o] : 0.f;
    float sm = v, sq = v*v;
    #pragma unroll
    for(int d=1; d<64; d<<=1){ sm += __shfl_xor(sm,d); sq += __shfl_xor(sq,d); }
    if(ln==0){ lds[(wv*16+o)*2] = sm; lds[(wv*16+o)*2+1] = sq; }
  }
  __syncthreads();
  if(tid < 32){
    int o = tid>>1, kd = tid&1;
    float S = ((lds[(0*16+o)*2+kd] + lds[(1*16+o)*2+kd])
             + (lds[(2*16+o)*2+kd] + lds[(3*16+o)*2+kd]));
    int blk = (b*32 + blockIdx.y)*16 + sseg;         // P=1024
    pacc[kd*16384 + o*1024 + blk] = S;               // CP = 16*1024
  }
}

// ---- final BN + SiLU in place on d_out ----
__global__ void k_final(float* __restrict__ out, const float* __restrict__ A,
                        const float* __restrict__ B){
  int idx = blockIdx.x*256 + threadIdx.x;
  int c = (idx>>16)&15;
  float y = fmaf(out[idx], A[c], B[c]);
  out[idx] = y / (1.f + expf(-y));
}

} // namespace

extern "C" void kernel_launch(void* const* d_in, const int* in_sizes, int n_in,
                              void* d_out, int out_size, void* d_ws, size_t ws_size,
                              hipStream_t stream){
  const float* x       = (const float*)d_in[0];
  const float* conv0_w = (const float*)d_in[1];
  const float* conv0_b = (const float*)d_in[2];
  const float* prelu0  = (const float*)d_in[3];
  const float* c1w  = (const float*)d_in[4];
  const float* c1b  = (const float*)d_in[5];
  const float* bn1g = (const float*)d_in[6];
  const float* bn1b = (const float*)d_in[7];
  const float* p1   = (const float*)d_in[8];
  const float* dww  = (const float*)d_in[9];
  const float* dwb  = (const float*)d_in[10];
  const float* bn2g = (const float*)d_in[11];
  const float* bn2b = (const float*)d_in[12];
  const float* p2   = (const float*)d_in[13];
  const float* c3w  = (const float*)d_in[14];
  const float* c3b  = (const float*)d_in[15];
  const float* bn3g = (const float*)d_in[16];
  const float* bn3b = (const float*)d_in[17];
  const float* p3   = (const float*)d_in[18];
  const float* hw   = (const float*)d_in[19];
  const float* hb   = (const float*)d_in[20];
  const float* obg  = (const float*)d_in[21];
  const float* obb  = (const float*)d_in[22];
  float* out = (float*)d_out;
  float* ws  = (float*)d_ws;

  // workspace (floats)
  float* xd   = ws;                 // 131072
  float* h    = xd + 131072;        // 524288
  float* A    = h  + 524288;        // 320
  float* B    = A  + 320;           // 320
  float* pacc = B  + 320;           // 81920
  float* t1   = pacc + 81920;       // 2621440
  float* t2   = t1 + 2621440;       // 2621440
  float* ts   = t2 + 2621440;       // 524288
  float* gv   = t1;                 // 4194304 aliases t1+t2 (dead by head)

  k_down <<<512,  256, 0, stream>>>(x, xd);
  k_conv0<<<2048, 256, 0, stream>>>(xd, conv0_w, conv0_b, prelu0, h);

  for(int i=0; i<3; i++){
    k_c1  <<<dim3(8,64,Bn), 256, 0, stream>>>(h, c1w + i*20480, c1b + i*320, t1, pacc);
    k_fin <<<320, 256, 0, stream>>>(pacc, 128, 1.f/8192.f, bn1g+i*320, bn1b+i*320, A, B);
    k_dw_s<<<10240, 256, 0, stream>>>(t1, dww + i*2880, dwb + i*320, A, B, p1+i, t2, pacc);
    k_fin <<<320, 256, 0, stream>>>(pacc, 32, 1.f/8192.f, bn2g+i*320, bn2b+i*320, A, B);
    k_c3  <<<dim3(256,Bn), 256, 0, stream>>>(t2, c3w + i*20480, c3b + i*64, A, B, p2+i, ts, pacc);
    k_fin <<<64, 256, 0, stream>>>(pacc, 512, 1.f/8192.f, bn3g+i*64, bn3b+i*64, A, B);
    k_addres<<<2048, 256, 0, stream>>>(ts, h, A, B, p3+i);
  }

  k_head_t<<<512, 256, 0, stream>>>(h, hw, hb, gv);
  k_slice <<<dim3(16,32,Bn), 256, 0, stream>>>(x, gv, out, pacc);
  k_fin   <<<16, 256, 0, stream>>>(pacc, 1024, 1.f/131072.f, obg, obb, A, B);
  k_final <<<8192, 256, 0, stream>>>(out, A, B);
}